// Round 1
// baseline (1183.318 us; speedup 1.0000x reference)
//
#include <hip/hip_runtime.h>
#include <hip/hip_bf16.h>
#include <float.h>

// Problem constants
#define BATCH 32
#define DIM   128
#define HW    4096          // 64*64
#define NPOS  131072        // 32*4096
#define K     512
#define ZSTRIDE_B 524288    // DIM*HW

// Output layout (floats, concatenated in reference return order)
#define Q_OFF     0
#define LOSS_OFF  16777216
#define IDX_OFF   16777217
#define NEMB_OFF  16908289
#define NCS_OFF   16973825
#define NEA_OFF   16974337

// Workspace layout (floats)
#define WS_E2    0
#define WS_ENC   512
#define WS_ESUM  1024
#define WS_LOSS  66560

// ---------------------------------------------------------------------------
// Kernel 0: per-code squared norms  e2[k] = sum_d emb[d*K+k]^2
__global__ __launch_bounds__(512) void k_e2(const float* __restrict__ emb,
                                            float* __restrict__ e2) {
    int k = threadIdx.x;
    float s = 0.f;
    #pragma unroll 8
    for (int d = 0; d < DIM; ++d) {
        float v = emb[d * K + k];
        s = fmaf(v, v, s);
    }
    e2[k] = s;
}

// ---------------------------------------------------------------------------
// Kernel 1: assignment + quantized output + indices + loss partial
// Block: 256 threads; each block owns 64 consecutive positions (same batch b).
// Tile: 64 pos x 128 codes, K-chunks of 128, D-chunks of 32.
// Thread micro-tile: 4 pos x 8 codes. pg = tid>>4 (0..15), cg = tid&15.
// Thread's codes within chunk: c = 16*j + cg (j=0..7), stored swizzled in LDS
// at es[d][cg*8+j] so each thread reads 2 contiguous float4.
__global__ __launch_bounds__(256) void k_assign(const float* __restrict__ z,
                                                const float* __restrict__ emb,
                                                const float* __restrict__ e2,
                                                float* __restrict__ out,
                                                float* __restrict__ lossAcc) {
    __shared__ float xs[32][64];     // [d][pos]
    __shared__ float es[32][128];    // [d][cg*8+j] swizzled
    __shared__ int   bidx[64];
    __shared__ float wred[4];

    const int tid = threadIdx.x;
    const int pg = tid >> 4;         // 0..15 -> positions pg*4..pg*4+3
    const int cg = tid & 15;         // 0..15 -> codes 16*j+cg
    const int n0 = blockIdx.x * 64;
    const int b  = n0 >> 12;
    const int hw0 = n0 & 4095;
    const float* zb = z + b * ZSTRIDE_B + hw0;

    float bestD[4];
    int   bestI[4];
    #pragma unroll
    for (int i = 0; i < 4; ++i) { bestD[i] = FLT_MAX; bestI[i] = 0x7fffffff; }

    for (int kc = 0; kc < 4; ++kc) {
        const int c0 = kc * 128;
        float acc[4][8];
        #pragma unroll
        for (int i = 0; i < 4; ++i)
            #pragma unroll
            for (int j = 0; j < 8; ++j) acc[i][j] = 0.f;

        for (int dc = 0; dc < 4; ++dc) {
            const int d0 = dc * 32;
            __syncthreads();  // protect LDS reuse from previous tile's compute
            // stage x-tile: 32 dims x 64 pos (coalesced 64-wide rows)
            #pragma unroll
            for (int r = 0; r < 8; ++r) {
                int lin = tid + r * 256;
                int d = lin >> 6, i = lin & 63;
                xs[d][i] = zb[(d0 + d) * HW + i];
            }
            // stage e-tile: 32 dims x 128 codes, swizzled store
            #pragma unroll
            for (int r = 0; r < 16; ++r) {
                int lin = tid + r * 256;
                int dd = lin >> 7, c = lin & 127;
                int loc = (c & 15) * 8 + (c >> 4);
                es[dd][loc] = emb[(d0 + dd) * K + c0 + c];
            }
            __syncthreads();
            #pragma unroll 4
            for (int d = 0; d < 32; ++d) {
                float4 xv = *(const float4*)(&xs[d][pg * 4]);
                float4 ea = *(const float4*)(&es[d][cg * 8]);
                float4 eb = *(const float4*)(&es[d][cg * 8 + 4]);
                float xr[4] = {xv.x, xv.y, xv.z, xv.w};
                float er[8] = {ea.x, ea.y, ea.z, ea.w, eb.x, eb.y, eb.z, eb.w};
                #pragma unroll
                for (int i = 0; i < 4; ++i)
                    #pragma unroll
                    for (int j = 0; j < 8; ++j)
                        acc[i][j] = fmaf(xr[i], er[j], acc[i][j]);
            }
        }
        // scores for this K-chunk; j ascending => code ids ascending (tie: first wins)
        #pragma unroll
        for (int j = 0; j < 8; ++j) {
            int c = c0 + 16 * j + cg;
            float ee = e2[c];
            #pragma unroll
            for (int i = 0; i < 4; ++i) {
                float s = fmaf(-2.f, acc[i][j], ee);
                if (s < bestD[i] || (s == bestD[i] && c < bestI[i])) {
                    bestD[i] = s; bestI[i] = c;
                }
            }
        }
    }

    // reduce across the 16 lanes (cg) sharing each position group (same wave)
    #pragma unroll
    for (int m = 8; m >= 1; m >>= 1) {
        #pragma unroll
        for (int i = 0; i < 4; ++i) {
            float od = __shfl_xor(bestD[i], m);
            int   oi = __shfl_xor(bestI[i], m);
            if (od < bestD[i] || (od == bestD[i] && oi < bestI[i])) {
                bestD[i] = od; bestI[i] = oi;
            }
        }
    }
    if (cg == 0) {
        #pragma unroll
        for (int i = 0; i < 4; ++i) bidx[pg * 4 + i] = bestI[i];
    }
    __syncthreads();

    // write indices (as float; values are small exact ints)
    if (tid < 64) out[IDX_OFF + n0 + tid] = (float)bidx[tid];

    // quantized output + loss partial: 64 pos x 128 dims = 8192 elems
    float lsum = 0.f;
    #pragma unroll 4
    for (int r = 0; r < 32; ++r) {
        int lin = tid + r * 256;
        int d = lin >> 6, i = lin & 63;
        float q  = emb[d * K + bidx[i]];
        float zz = zb[d * HW + i];
        out[Q_OFF + b * ZSTRIDE_B + d * HW + hw0 + i] = q;
        float df = q - zz;
        lsum = fmaf(df, df, lsum);
    }
    // block-reduce lsum
    #pragma unroll
    for (int m = 32; m >= 1; m >>= 1) lsum += __shfl_xor(lsum, m);
    int wave = tid >> 6;
    if ((tid & 63) == 0) wred[wave] = lsum;
    __syncthreads();
    if (tid == 0) {
        float t = wred[0] + wred[1] + wred[2] + wred[3];
        atomicAdd(lossAcc, t);
    }
}

// ---------------------------------------------------------------------------
// Kernel 2: EMA accumulators via atomics.
// Block: 256 threads, 256 consecutive positions (same b). Coalesced z reads.
__global__ __launch_bounds__(256) void k_ema(const float* __restrict__ z,
                                             const float* __restrict__ out,
                                             float* __restrict__ enc,
                                             float* __restrict__ esum) {
    int tid = threadIdx.x;
    int n = blockIdx.x * 256 + tid;
    int k = (int)out[IDX_OFF + n];
    int b = n >> 12, hw = n & 4095;
    atomicAdd(&enc[k], 1.0f);
    const float* zb = z + b * ZSTRIDE_B + hw;
    #pragma unroll 4
    for (int d = 0; d < DIM; ++d) {
        atomicAdd(&esum[d * K + k], zb[d * HW]);
    }
}

// ---------------------------------------------------------------------------
// Kernel 3: finalize EMA + loss. Single block, 512 threads (one per code).
__global__ __launch_bounds__(512) void k_final(const float* __restrict__ enc,
                                               const float* __restrict__ esum,
                                               const float* __restrict__ cs_in,
                                               const float* __restrict__ eavg_in,
                                               const float* __restrict__ lossAcc,
                                               float* __restrict__ out) {
    __shared__ float red[512];
    int k = threadIdx.x;
    float ncs = fmaf(cs_in[k], 0.99f, 0.01f * enc[k]);
    red[k] = ncs;
    __syncthreads();
    for (int s = 256; s > 0; s >>= 1) {
        if (k < s) red[k] += red[k + s];
        __syncthreads();
    }
    float nn = fmaxf(red[0], 1e-5f);
    float cs = (ncs + 1e-5f) / (nn + (float)K * 1e-5f) * nn;
    out[NCS_OFF + k] = ncs;
    if (k == 0) out[LOSS_OFF] = lossAcc[0] * 1.25f / 16777216.0f;
    float inv_cs = 1.0f / cs;
    #pragma unroll 4
    for (int d = 0; d < DIM; ++d) {
        float ea = fmaf(eavg_in[d * K + k], 0.99f, 0.01f * esum[d * K + k]);
        out[NEA_OFF + d * K + k] = ea;
        out[NEMB_OFF + d * K + k] = ea * inv_cs;
    }
}

// ---------------------------------------------------------------------------
extern "C" void kernel_launch(void* const* d_in, const int* in_sizes, int n_in,
                              void* d_out, int out_size, void* d_ws, size_t ws_size,
                              hipStream_t stream) {
    const float* z     = (const float*)d_in[0];
    const float* emb   = (const float*)d_in[1];
    const float* cs_in = (const float*)d_in[2];
    const float* eavg  = (const float*)d_in[3];
    float* out = (float*)d_out;
    float* wsF = (float*)d_ws;

    float* e2      = wsF + WS_E2;
    float* enc     = wsF + WS_ENC;
    float* esum    = wsF + WS_ESUM;
    float* lossAcc = wsF + WS_LOSS;

    // zero enc_sum + embed_sum + loss accumulator (ws is poisoned before each call)
    hipMemsetAsync((char*)d_ws + WS_ENC * sizeof(float), 0,
                   (512 + 65536 + 1) * sizeof(float), stream);

    k_e2<<<1, 512, 0, stream>>>(emb, e2);
    k_assign<<<NPOS / 64, 256, 0, stream>>>(z, emb, e2, out, lossAcc);
    k_ema<<<NPOS / 256, 256, 0, stream>>>(z, out, enc, esum);
    k_final<<<1, 512, 0, stream>>>(enc, esum, cs_in, eavg, lossAcc, out);
}

// Round 2
// 571.401 us; speedup vs baseline: 2.0709x; 2.0709x over previous
//
#include <hip/hip_runtime.h>
#include <hip/hip_bf16.h>
#include <float.h>

// Problem constants
#define BATCH 32
#define DIM   128
#define HW    4096          // 64*64
#define NPOS  131072        // 32*4096
#define K     512
#define ZSTRIDE_B 524288    // DIM*HW

// Output layout (floats, concatenated in reference return order)
#define Q_OFF     0
#define LOSS_OFF  16777216
#define IDX_OFF   16777217
#define NEMB_OFF  16908289
#define NCS_OFF   16973825
#define NEA_OFF   16974337

// Workspace layout (floats)
#define WS_E2    0
#define WS_ENC   512
#define WS_ESUM  1024
#define WS_LOSS  66560

// ---------------------------------------------------------------------------
// Kernel 0: per-code squared norms  e2[k] = sum_d emb[d*K+k]^2
__global__ __launch_bounds__(512) void k_e2(const float* __restrict__ emb,
                                            float* __restrict__ e2) {
    int k = threadIdx.x;
    float s = 0.f;
    #pragma unroll 8
    for (int d = 0; d < DIM; ++d) {
        float v = emb[d * K + k];
        s = fmaf(v, v, s);
    }
    e2[k] = s;
}

// ---------------------------------------------------------------------------
// Kernel 1: assignment + quantized output + indices + loss partial
// Block: 256 threads; each block owns 64 consecutive positions (same batch b).
// Tile: 64 pos x 128 codes, K-chunks of 128, D-chunks of 32.
// Thread micro-tile: 4 pos x 8 codes. pg = tid>>4 (0..15), cg = tid&15.
__global__ __launch_bounds__(256) void k_assign(const float* __restrict__ z,
                                                const float* __restrict__ emb,
                                                const float* __restrict__ e2,
                                                float* __restrict__ out,
                                                float* __restrict__ lossAcc) {
    __shared__ float xs[32][64];     // [d][pos]
    __shared__ float es[32][128];    // [d][cg*8+j] swizzled
    __shared__ int   bidx[64];
    __shared__ float wred[4];

    const int tid = threadIdx.x;
    const int pg = tid >> 4;         // 0..15 -> positions pg*4..pg*4+3
    const int cg = tid & 15;         // 0..15 -> codes 16*j+cg
    const int n0 = blockIdx.x * 64;
    const int b  = n0 >> 12;
    const int hw0 = n0 & 4095;
    const float* zb = z + b * ZSTRIDE_B + hw0;

    float bestD[4];
    int   bestI[4];
    #pragma unroll
    for (int i = 0; i < 4; ++i) { bestD[i] = FLT_MAX; bestI[i] = 0x7fffffff; }

    for (int kc = 0; kc < 4; ++kc) {
        const int c0 = kc * 128;
        float acc[4][8];
        #pragma unroll
        for (int i = 0; i < 4; ++i)
            #pragma unroll
            for (int j = 0; j < 8; ++j) acc[i][j] = 0.f;

        for (int dc = 0; dc < 4; ++dc) {
            const int d0 = dc * 32;
            __syncthreads();  // protect LDS reuse from previous tile's compute
            // stage x-tile: 32 dims x 64 pos (coalesced 64-wide rows)
            #pragma unroll
            for (int r = 0; r < 8; ++r) {
                int lin = tid + r * 256;
                int d = lin >> 6, i = lin & 63;
                xs[d][i] = zb[(d0 + d) * HW + i];
            }
            // stage e-tile: 32 dims x 128 codes, swizzled store
            #pragma unroll
            for (int r = 0; r < 16; ++r) {
                int lin = tid + r * 256;
                int dd = lin >> 7, c = lin & 127;
                int loc = (c & 15) * 8 + (c >> 4);
                es[dd][loc] = emb[(d0 + dd) * K + c0 + c];
            }
            __syncthreads();
            #pragma unroll 4
            for (int d = 0; d < 32; ++d) {
                float4 xv = *(const float4*)(&xs[d][pg * 4]);
                float4 ea = *(const float4*)(&es[d][cg * 8]);
                float4 eb = *(const float4*)(&es[d][cg * 8 + 4]);
                float xr[4] = {xv.x, xv.y, xv.z, xv.w};
                float er[8] = {ea.x, ea.y, ea.z, ea.w, eb.x, eb.y, eb.z, eb.w};
                #pragma unroll
                for (int i = 0; i < 4; ++i)
                    #pragma unroll
                    for (int j = 0; j < 8; ++j)
                        acc[i][j] = fmaf(xr[i], er[j], acc[i][j]);
            }
        }
        // scores for this K-chunk; j ascending => code ids ascending (tie: first wins)
        #pragma unroll
        for (int j = 0; j < 8; ++j) {
            int c = c0 + 16 * j + cg;
            float ee = e2[c];
            #pragma unroll
            for (int i = 0; i < 4; ++i) {
                float s = fmaf(-2.f, acc[i][j], ee);
                if (s < bestD[i] || (s == bestD[i] && c < bestI[i])) {
                    bestD[i] = s; bestI[i] = c;
                }
            }
        }
    }

    // reduce across the 16 lanes (cg) sharing each position group (same wave)
    #pragma unroll
    for (int m = 8; m >= 1; m >>= 1) {
        #pragma unroll
        for (int i = 0; i < 4; ++i) {
            float od = __shfl_xor(bestD[i], m);
            int   oi = __shfl_xor(bestI[i], m);
            if (od < bestD[i] || (od == bestD[i] && oi < bestI[i])) {
                bestD[i] = od; bestI[i] = oi;
            }
        }
    }
    if (cg == 0) {
        #pragma unroll
        for (int i = 0; i < 4; ++i) bidx[pg * 4 + i] = bestI[i];
    }
    __syncthreads();

    // write indices (as float; values are small exact ints)
    if (tid < 64) out[IDX_OFF + n0 + tid] = (float)bidx[tid];

    // quantized output + loss partial: 64 pos x 128 dims = 8192 elems
    float lsum = 0.f;
    #pragma unroll 4
    for (int r = 0; r < 32; ++r) {
        int lin = tid + r * 256;
        int d = lin >> 6, i = lin & 63;
        float q  = emb[d * K + bidx[i]];
        float zz = zb[d * HW + i];
        out[Q_OFF + b * ZSTRIDE_B + d * HW + hw0 + i] = q;
        float df = q - zz;
        lsum = fmaf(df, df, lsum);
    }
    // block-reduce lsum
    #pragma unroll
    for (int m = 32; m >= 1; m >>= 1) lsum += __shfl_xor(lsum, m);
    int wave = tid >> 6;
    if ((tid & 63) == 0) wred[wave] = lsum;
    __syncthreads();
    if (tid == 0) {
        float t = wred[0] + wred[1] + wred[2] + wred[3];
        atomicAdd(lossAcc, t);
    }
}

// ---------------------------------------------------------------------------
// Kernel 2 (v2): EMA accumulators via LDS privatization.
// Grid: (BATCH/GB) * (DIM/DC) = 8 * 16 = 128 blocks of 256 threads.
// Each block: GB=4 batches worth of positions, DC=8 dims, LDS acc[DC][K]=16KB.
// Coalesced float4 z reads; scalar idx reads (IDX_OFF is odd -> 4B aligned).
// Flush: 4096 coalesced global atomics per block (524K total vs 16.7M before).
#define DC 8
#define GB 4
__global__ __launch_bounds__(256) void k_ema2(const float* __restrict__ z,
                                              const float* __restrict__ out,
                                              float* __restrict__ enc,
                                              float* __restrict__ esum) {
    __shared__ float acc[DC][K];   // 16 KB
    __shared__ float cnt[K];       // 2 KB (used by dchunk==0 blocks)

    const int tid = threadIdx.x;
    const int dchunk = blockIdx.x & 15;   // 16 d-chunks
    const int bgrp   = blockIdx.x >> 4;   // 8 b-groups
    const int d0 = dchunk * DC;
    const bool doCnt = (dchunk == 0);

    for (int i = tid; i < DC * K; i += 256) ((float*)acc)[i] = 0.f;
    if (doCnt) for (int i = tid; i < K; i += 256) cnt[i] = 0.f;
    __syncthreads();

    for (int bb = 0; bb < GB; ++bb) {
        const int b = bgrp * GB + bb;
        const float* zb  = z + b * ZSTRIDE_B;
        const float* idp = out + IDX_OFF + b * HW;
        for (int t = 0; t < HW; t += 1024) {
            const int p = t + 4 * tid;
            int k0 = (int)idp[p + 0];
            int k1 = (int)idp[p + 1];
            int k2 = (int)idp[p + 2];
            int k3 = (int)idp[p + 3];
            if (doCnt) {
                atomicAdd(&cnt[k0], 1.f); atomicAdd(&cnt[k1], 1.f);
                atomicAdd(&cnt[k2], 1.f); atomicAdd(&cnt[k3], 1.f);
            }
            #pragma unroll
            for (int d = 0; d < DC; ++d) {
                float4 zv = *(const float4*)(zb + (d0 + d) * HW + p);
                atomicAdd(&acc[d][k0], zv.x);
                atomicAdd(&acc[d][k1], zv.y);
                atomicAdd(&acc[d][k2], zv.z);
                atomicAdd(&acc[d][k3], zv.w);
            }
        }
    }
    __syncthreads();

    // flush: consecutive-address atomics (wave hits 64 consecutive floats)
    for (int i = tid; i < DC * K; i += 256) {
        int d = i >> 9, k = i & 511;
        atomicAdd(&esum[(d0 + d) * K + k], acc[d][k]);
    }
    if (doCnt) for (int i = tid; i < K; i += 256) atomicAdd(&enc[i], cnt[i]);
}

// ---------------------------------------------------------------------------
// Kernel 3: finalize EMA + loss. Single block, 512 threads (one per code).
__global__ __launch_bounds__(512) void k_final(const float* __restrict__ enc,
                                               const float* __restrict__ esum,
                                               const float* __restrict__ cs_in,
                                               const float* __restrict__ eavg_in,
                                               const float* __restrict__ lossAcc,
                                               float* __restrict__ out) {
    __shared__ float red[512];
    int k = threadIdx.x;
    float ncs = fmaf(cs_in[k], 0.99f, 0.01f * enc[k]);
    red[k] = ncs;
    __syncthreads();
    for (int s = 256; s > 0; s >>= 1) {
        if (k < s) red[k] += red[k + s];
        __syncthreads();
    }
    float nn = fmaxf(red[0], 1e-5f);
    float cs = (ncs + 1e-5f) / (nn + (float)K * 1e-5f) * nn;
    out[NCS_OFF + k] = ncs;
    if (k == 0) out[LOSS_OFF] = lossAcc[0] * 1.25f / 16777216.0f;
    float inv_cs = 1.0f / cs;
    #pragma unroll 4
    for (int d = 0; d < DIM; ++d) {
        float ea = fmaf(eavg_in[d * K + k], 0.99f, 0.01f * esum[d * K + k]);
        out[NEA_OFF + d * K + k] = ea;
        out[NEMB_OFF + d * K + k] = ea * inv_cs;
    }
}

// ---------------------------------------------------------------------------
extern "C" void kernel_launch(void* const* d_in, const int* in_sizes, int n_in,
                              void* d_out, int out_size, void* d_ws, size_t ws_size,
                              hipStream_t stream) {
    const float* z     = (const float*)d_in[0];
    const float* emb   = (const float*)d_in[1];
    const float* cs_in = (const float*)d_in[2];
    const float* eavg  = (const float*)d_in[3];
    float* out = (float*)d_out;
    float* wsF = (float*)d_ws;

    float* e2      = wsF + WS_E2;
    float* enc     = wsF + WS_ENC;
    float* esum    = wsF + WS_ESUM;
    float* lossAcc = wsF + WS_LOSS;

    // zero enc_sum + embed_sum + loss accumulator (ws is poisoned before each call)
    hipMemsetAsync((char*)d_ws + WS_ENC * sizeof(float), 0,
                   (512 + 65536 + 1) * sizeof(float), stream);

    k_e2<<<1, 512, 0, stream>>>(emb, e2);
    k_assign<<<NPOS / 64, 256, 0, stream>>>(z, emb, e2, out, lossAcc);
    k_ema2<<<128, 256, 0, stream>>>(z, out, enc, esum);
    k_final<<<1, 512, 0, stream>>>(enc, esum, cs_in, eavg, lossAcc, out);
}

// Round 3
// 392.779 us; speedup vs baseline: 3.0127x; 1.4548x over previous
//
#include <hip/hip_runtime.h>
#include <hip/hip_bf16.h>
#include <float.h>

typedef _Float16 f16;
typedef __attribute__((ext_vector_type(8))) _Float16 half8;
typedef __attribute__((ext_vector_type(4))) float floatx4;

// Problem constants
#define DIM   128
#define HW    4096
#define NPOS  131072
#define K     512
#define ZSTRIDE_B 524288

// Output layout (floats)
#define Q_OFF     0
#define LOSS_OFF  16777216
#define IDX_OFF   16777217
#define NEMB_OFF  16908289
#define NCS_OFF   16973825
#define NEA_OFF   16974337

// Workspace layout (floats). e_hiT/e_loT OVERLAY the esum region: k_prep writes
// them, k_assign reads them, then esum is memset to 0 before k_ema2 uses it.
#define WS_E2    0
#define WS_ENC   512
#define WS_ESUM  1024
#define WS_EHI   1024          // f16[K*DIM] = 32768 floats
#define WS_ELO   33792         // f16[K*DIM] = 32768 floats (ends at 66560)
#define WS_LOSS  66560

#define XST 136   // xs row stride (f16): 128 d + 8 pad -> 272B, 16B-aligned, 2-way banks
#define EST 40    // es row stride (f16): 32 d + 8 pad  ->  80B, 16B-aligned, 2-way banks

// ---------------------------------------------------------------------------
// k_prep: split codebook into f16 hi/lo, TRANSPOSED to [K][DIM] for staging.
__global__ __launch_bounds__(256) void k_prep(const float* __restrict__ emb,
                                              f16* __restrict__ ehiT,
                                              f16* __restrict__ eloT) {
    int lin = blockIdx.x * 256 + threadIdx.x;   // 65536 threads
    int d = lin >> 9, k = lin & 511;
    float v = emb[lin];                          // coalesced read
    f16 h = (f16)v;
    f16 l = (f16)(v - (float)h);
    ehiT[k * DIM + d] = h;                       // scattered 2B writes (one-shot, tiny)
    eloT[k * DIM + d] = l;
}

// ---------------------------------------------------------------------------
// k_e2: exact fp32 per-code squared norms
__global__ __launch_bounds__(512) void k_e2(const float* __restrict__ emb,
                                            float* __restrict__ e2) {
    int k = threadIdx.x;
    float s = 0.f;
    #pragma unroll 8
    for (int d = 0; d < DIM; ++d) {
        float v = emb[d * K + k];
        s = fmaf(v, v, s);
    }
    e2[k] = s;
}

// ---------------------------------------------------------------------------
// k_assign (MFMA): 64 positions/block, all 512 codes, D=128.
// score = e2[c] - 2*dot(x,e); dot via 3-pass f16-split MFMA (hh + lh + hl).
// Wave w covers codes [nc*256 + w*64, +64) per 256-code chunk.
__global__ __launch_bounds__(256) void k_assign(const float* __restrict__ z,
                                                const float* __restrict__ emb,
                                                const f16* __restrict__ ehiT,
                                                const f16* __restrict__ eloT,
                                                const float* __restrict__ e2,
                                                float* __restrict__ out,
                                                float* __restrict__ lossAcc) {
    __shared__ f16 xs_h[64 * XST];
    __shared__ f16 xs_l[64 * XST];
    __shared__ f16 es_h[256 * EST];
    __shared__ f16 es_l[256 * EST];
    __shared__ float wbD[256];
    __shared__ int   wbI[256];
    __shared__ int   bidx[64];
    __shared__ float wred[4];

    const int tid  = threadIdx.x;
    const int lane = tid & 63;
    const int wv   = tid >> 6;
    const int n0   = blockIdx.x * 64;
    const int b    = n0 >> 12;
    const int hw0  = n0 & 4095;
    const float* zb = z + b * ZSTRIDE_B + hw0;
    const int l15  = lane & 15;
    const int quad = lane >> 4;

    // ---- stage X split (64 pos x 128 d), d-pair packed u32 LDS writes
    #pragma unroll
    for (int it = 0; it < 16; ++it) {
        int lin = tid + it * 256;
        int i  = lin & 63;          // position (lanes consecutive -> coalesced)
        int dp = lin >> 6;          // d-pair 0..63
        float v0 = zb[(2 * dp) * HW + i];
        float v1 = zb[(2 * dp + 1) * HW + i];
        f16 h0 = (f16)v0; f16 l0 = (f16)(v0 - (float)h0);
        f16 h1 = (f16)v1; f16 l1 = (f16)(v1 - (float)h1);
        union { f16 h[2]; unsigned int u; } ph, pl;
        ph.h[0] = h0; ph.h[1] = h1;
        pl.h[0] = l0; pl.h[1] = l1;
        *(unsigned int*)&xs_h[i * XST + 2 * dp] = ph.u;
        *(unsigned int*)&xs_l[i * XST + 2 * dp] = pl.u;
    }

    float bestD[4][4];
    int   bestI[4][4];
    #pragma unroll
    for (int t = 0; t < 4; ++t)
        #pragma unroll
        for (int r = 0; r < 4; ++r) { bestD[t][r] = FLT_MAX; bestI[t][r] = 0x7fffffff; }

    const unsigned int* gh = (const unsigned int*)ehiT;
    const unsigned int* gl = (const unsigned int*)eloT;

    for (int nc = 0; nc < 2; ++nc) {
        floatx4 acc[4][4];
        #pragma unroll
        for (int t = 0; t < 4; ++t)
            #pragma unroll
            for (int nt = 0; nt < 4; ++nt) acc[t][nt] = (floatx4){0.f, 0.f, 0.f, 0.f};

        for (int dc = 0; dc < 4; ++dc) {
            __syncthreads();
            // stage es for (nc,dc): 256 rows x 16 u32 per array, coalesced reads
            #pragma unroll
            for (int it = 0; it < 16; ++it) {
                int lin = tid + it * 256;
                int c = lin >> 4, col = lin & 15;
                int gidx = (nc * 256 + c) * 64 + dc * 16 + col;
                unsigned int vh = gh[gidx];
                unsigned int vl = gl[gidx];
                *(unsigned int*)&es_h[c * EST + 2 * col] = vh;
                *(unsigned int*)&es_l[c * EST + 2 * col] = vl;
            }
            __syncthreads();
            // A fragments: A[m = t*16 + (lane&15)][k = quad*8 + j]
            half8 ah[4], al[4];
            #pragma unroll
            for (int t = 0; t < 4; ++t) {
                int off = (t * 16 + l15) * XST + dc * 32 + quad * 8;
                ah[t] = *(const half8*)&xs_h[off];
                al[t] = *(const half8*)&xs_l[off];
            }
            #pragma unroll
            for (int nt = 0; nt < 4; ++nt) {
                int cr = wv * 64 + nt * 16 + l15;       // B[n = lane&15][k = quad*8+j]
                int boff = cr * EST + quad * 8;
                half8 bh = *(const half8*)&es_h[boff];
                half8 bl = *(const half8*)&es_l[boff];
                #pragma unroll
                for (int t = 0; t < 4; ++t) {
                    acc[t][nt] = __builtin_amdgcn_mfma_f32_16x16x32_f16(ah[t], bh, acc[t][nt], 0, 0, 0);
                    acc[t][nt] = __builtin_amdgcn_mfma_f32_16x16x32_f16(al[t], bh, acc[t][nt], 0, 0, 0);
                    acc[t][nt] = __builtin_amdgcn_mfma_f32_16x16x32_f16(ah[t], bl, acc[t][nt], 0, 0, 0);
                }
            }
        }
        // fold scores into best (codes ascend across nc,nt for fixed lane -> strict <)
        #pragma unroll
        for (int nt = 0; nt < 4; ++nt) {
            int c = nc * 256 + wv * 64 + nt * 16 + l15;
            float ee = e2[c];
            #pragma unroll
            for (int t = 0; t < 4; ++t)
                #pragma unroll
                for (int r = 0; r < 4; ++r) {
                    float s = fmaf(-2.f, acc[t][nt][r], ee);
                    if (s < bestD[t][r]) { bestD[t][r] = s; bestI[t][r] = c; }
                }
        }
    }

    // reduce across the 16 lanes holding different codes for the same rows
    #pragma unroll
    for (int mask = 1; mask <= 8; mask <<= 1) {
        #pragma unroll
        for (int t = 0; t < 4; ++t)
            #pragma unroll
            for (int r = 0; r < 4; ++r) {
                float od = __shfl_xor(bestD[t][r], mask, 64);
                int   oi = __shfl_xor(bestI[t][r], mask, 64);
                if (od < bestD[t][r] || (od == bestD[t][r] && oi < bestI[t][r])) {
                    bestD[t][r] = od; bestI[t][r] = oi;
                }
            }
    }
    if (l15 == 0) {
        #pragma unroll
        for (int t = 0; t < 4; ++t)
            #pragma unroll
            for (int r = 0; r < 4; ++r) {
                int m = t * 16 + quad * 4 + r;   // C layout: row=(lane>>4)*4+reg
                wbD[wv * 64 + m] = bestD[t][r];
                wbI[wv * 64 + m] = bestI[t][r];
            }
    }
    __syncthreads();
    if (tid < 64) {
        float bd = wbD[tid]; int bi = wbI[tid];
        #pragma unroll
        for (int w = 1; w < 4; ++w) {
            float od = wbD[w * 64 + tid]; int oi = wbI[w * 64 + tid];
            if (od < bd || (od == bd && oi < bi)) { bd = od; bi = oi; }
        }
        bidx[tid] = bi;
        out[IDX_OFF + n0 + tid] = (float)bi;
    }
    __syncthreads();

    // epilogue: quantized output (exact fp32 codebook gather) + loss partial
    float lsum = 0.f;
    #pragma unroll 4
    for (int r = 0; r < 32; ++r) {
        int lin = tid + r * 256;
        int d = lin >> 6, i = lin & 63;
        float q  = emb[d * K + bidx[i]];
        float zz = zb[d * HW + i];
        out[Q_OFF + b * ZSTRIDE_B + d * HW + hw0 + i] = q;
        float df = q - zz;
        lsum = fmaf(df, df, lsum);
    }
    #pragma unroll
    for (int m = 32; m >= 1; m >>= 1) lsum += __shfl_xor(lsum, m, 64);
    if ((tid & 63) == 0) wred[wv] = lsum;
    __syncthreads();
    if (tid == 0) {
        float t = wred[0] + wred[1] + wred[2] + wred[3];
        atomicAdd(lossAcc, t);
    }
}

// ---------------------------------------------------------------------------
// k_ema2: LDS-privatized segment sums. 512 blocks (32 batches x 16 d-chunks).
#define DC 8
__global__ __launch_bounds__(256) void k_ema2(const float* __restrict__ z,
                                              const float* __restrict__ out,
                                              float* __restrict__ enc,
                                              float* __restrict__ esum) {
    __shared__ float acc[DC][K];   // 16 KB
    __shared__ float cnt[K];       // 2 KB

    const int tid = threadIdx.x;
    const int dchunk = blockIdx.x & 15;
    const int b      = blockIdx.x >> 4;
    const int d0 = dchunk * DC;
    const bool doCnt = (dchunk == 0);

    for (int i = tid; i < DC * K; i += 256) ((float*)acc)[i] = 0.f;
    if (doCnt) for (int i = tid; i < K; i += 256) cnt[i] = 0.f;
    __syncthreads();

    const float* zb  = z + b * ZSTRIDE_B;
    const float* idp = out + IDX_OFF + b * HW;
    for (int t = 0; t < HW; t += 1024) {
        const int p = t + 4 * tid;
        int k0 = (int)idp[p + 0];
        int k1 = (int)idp[p + 1];
        int k2 = (int)idp[p + 2];
        int k3 = (int)idp[p + 3];
        if (doCnt) {
            atomicAdd(&cnt[k0], 1.f); atomicAdd(&cnt[k1], 1.f);
            atomicAdd(&cnt[k2], 1.f); atomicAdd(&cnt[k3], 1.f);
        }
        #pragma unroll
        for (int d = 0; d < DC; ++d) {
            float4 zv = *(const float4*)(zb + (d0 + d) * HW + p);
            atomicAdd(&acc[d][k0], zv.x);
            atomicAdd(&acc[d][k1], zv.y);
            atomicAdd(&acc[d][k2], zv.z);
            atomicAdd(&acc[d][k3], zv.w);
        }
    }
    __syncthreads();

    for (int i = tid; i < DC * K; i += 256) {
        int d = i >> 9, k = i & 511;
        atomicAdd(&esum[(d0 + d) * K + k], acc[d][k]);
    }
    if (doCnt) for (int i = tid; i < K; i += 256) atomicAdd(&enc[i], cnt[i]);
}

// ---------------------------------------------------------------------------
__global__ __launch_bounds__(512) void k_final(const float* __restrict__ enc,
                                               const float* __restrict__ esum,
                                               const float* __restrict__ cs_in,
                                               const float* __restrict__ eavg_in,
                                               const float* __restrict__ lossAcc,
                                               float* __restrict__ out) {
    __shared__ float red[512];
    int k = threadIdx.x;
    float ncs = fmaf(cs_in[k], 0.99f, 0.01f * enc[k]);
    red[k] = ncs;
    __syncthreads();
    for (int s = 256; s > 0; s >>= 1) {
        if (k < s) red[k] += red[k + s];
        __syncthreads();
    }
    float nn = fmaxf(red[0], 1e-5f);
    float cs = (ncs + 1e-5f) / (nn + (float)K * 1e-5f) * nn;
    out[NCS_OFF + k] = ncs;
    if (k == 0) out[LOSS_OFF] = lossAcc[0] * 1.25f / 16777216.0f;
    float inv_cs = 1.0f / cs;
    #pragma unroll 4
    for (int d = 0; d < DIM; ++d) {
        float ea = fmaf(eavg_in[d * K + k], 0.99f, 0.01f * esum[d * K + k]);
        out[NEA_OFF + d * K + k] = ea;
        out[NEMB_OFF + d * K + k] = ea * inv_cs;
    }
}

// ---------------------------------------------------------------------------
extern "C" void kernel_launch(void* const* d_in, const int* in_sizes, int n_in,
                              void* d_out, int out_size, void* d_ws, size_t ws_size,
                              hipStream_t stream) {
    const float* z     = (const float*)d_in[0];
    const float* emb   = (const float*)d_in[1];
    const float* cs_in = (const float*)d_in[2];
    const float* eavg  = (const float*)d_in[3];
    float* out = (float*)d_out;
    float* wsF = (float*)d_ws;

    hipMemsetAsync(wsF + WS_ENC, 0, 512 * sizeof(float), stream);
    hipMemsetAsync(wsF + WS_LOSS, 0, sizeof(float), stream);

    k_prep<<<256, 256, 0, stream>>>(emb, (f16*)(wsF + WS_EHI), (f16*)(wsF + WS_ELO));
    k_e2<<<1, 512, 0, stream>>>(emb, wsF + WS_E2);
    k_assign<<<NPOS / 64, 256, 0, stream>>>(z, emb,
                                            (const f16*)(wsF + WS_EHI),
                                            (const f16*)(wsF + WS_ELO),
                                            wsF + WS_E2, out, wsF + WS_LOSS);
    // e_hiT/e_loT no longer needed: reclaim region as esum
    hipMemsetAsync(wsF + WS_ESUM, 0, 65536 * sizeof(float), stream);
    k_ema2<<<512, 256, 0, stream>>>(z, out, wsF + WS_ENC, wsF + WS_ESUM);
    k_final<<<1, 512, 0, stream>>>(wsF + WS_ENC, wsF + WS_ESUM, cs_in, eavg,
                                   wsF + WS_LOSS, out);
}